// Round 2
// baseline (6254.783 us; speedup 1.0000x reference)
//
#include <hip/hip_runtime.h>
#include <hip/hip_bf16.h>
#include <math.h>

// ---------------------------------------------------------------------------
// Problem constants (KAE forward, full batch)
// ---------------------------------------------------------------------------
#define NN   3072
#define NIN  784
#define E1D  500
#define E2D  500
#define E3D  2000
#define NZD  10
#define NCD  10

// ---------------------------------------------------------------------------
// Generic fp32 SGEMM: C = A(MxK) * B + bias
//   TRANSB=false: B is KxN row-major
//   TRANSB=true : B is NxK row-major (computes A * B^T) -- used for h @ h^T
// 128x128 tile, BK=8, 256 threads, 8x8 microtile.
// ---------------------------------------------------------------------------
#define TBM 128
#define TBN 128
#define TBK 8
#define TT  8

template <bool TRANSB>
__global__ __launch_bounds__(256)
void sgemm_kernel(const float* __restrict__ A, const float* __restrict__ B,
                  const float* __restrict__ bias, float* __restrict__ C,
                  int M, int N, int K)
{
    __shared__ float As[TBK][TBM + 4];
    __shared__ float Bs[TBK][TBN + 4];

    const int tid = threadIdx.x;           // 0..255
    const int bm  = blockIdx.y * TBM;
    const int bn  = blockIdx.x * TBN;
    const int tr  = (tid / 16) * TT;       // row offset in tile
    const int tc  = (tid % 16) * TT;       // col offset in tile

    float acc[TT][TT];
#pragma unroll
    for (int i = 0; i < TT; ++i)
#pragma unroll
        for (int j = 0; j < TT; ++j) acc[i][j] = 0.f;

    const int la_k = tid % TBK;            // 0..7
    const int la_m = tid / TBK;            // 0..31

    for (int k0 = 0; k0 < K; k0 += TBK) {
        // --- stage A tile: As[k][m] = A[bm+m][k0+k]  (1024 elems, 4/thread)
#pragma unroll
        for (int p = 0; p < 4; ++p) {
            int m  = la_m + p * 32;
            int gm = bm + m, gk = k0 + la_k;
            float v = 0.f;
            if (gm < M && gk < K) v = A[(size_t)gm * K + gk];
            As[la_k][m] = v;
        }
        // --- stage B tile: Bs[k][n]  (1024 elems, 4/thread)
        if (!TRANSB) {
#pragma unroll
            for (int p = 0; p < 4; ++p) {
                int idx = tid + p * 256;       // 0..1023
                int kk  = idx / TBN;           // 0..7
                int n   = idx % TBN;           // 0..127
                int gk = k0 + kk, gn = bn + n;
                float v = 0.f;
                if (gk < K && gn < N) v = B[(size_t)gk * N + gn];
                Bs[kk][n] = v;
            }
        } else {
#pragma unroll
            for (int p = 0; p < 4; ++p) {
                int n  = tid / 8 + p * 32;
                int gk = k0 + la_k, gn = bn + n;
                float v = 0.f;
                if (gk < K && gn < N) v = B[(size_t)gn * K + gk];
                Bs[la_k][n] = v;
            }
        }
        __syncthreads();

#pragma unroll
        for (int kk = 0; kk < TBK; ++kk) {
            float a[TT], b[TT];
#pragma unroll
            for (int i = 0; i < TT; ++i) a[i] = As[kk][tr + i];
#pragma unroll
            for (int j = 0; j < TT; ++j) b[j] = Bs[kk][tc + j];
#pragma unroll
            for (int i = 0; i < TT; ++i)
#pragma unroll
                for (int j = 0; j < TT; ++j)
                    acc[i][j] = fmaf(a[i], b[j], acc[i][j]);
        }
        __syncthreads();
    }

#pragma unroll
    for (int i = 0; i < TT; ++i) {
        int gm = bm + tr + i;
        if (gm >= M) continue;
#pragma unroll
        for (int j = 0; j < TT; ++j) {
            int gn = bn + tc + j;
            if (gn < N) {
                float v = acc[i][j];
                if (bias != nullptr) v += bias[gn];
                C[(size_t)gm * N + gn] = v;
            }
        }
    }
}

// ---------------------------------------------------------------------------
// s[i] = lin[i][i]
// ---------------------------------------------------------------------------
__global__ void diag_kernel(const float* __restrict__ lin, float* __restrict__ s, int N)
{
    int i = blockIdx.x * blockDim.x + threadIdx.x;
    if (i < N) s[i] = lin[(size_t)i * N + i];
}

// ---------------------------------------------------------------------------
// rowsum[i] = sum_j exp(-0.5*sq_ij) * (i != j)
// ---------------------------------------------------------------------------
__global__ __launch_bounds__(256)
void rowsumA_kernel(const float* __restrict__ lin, const float* __restrict__ s,
                    float* __restrict__ rowsum, int N)
{
    int i = blockIdx.x;
    float si = s[i];
    float acc = 0.f;
    for (int j = threadIdx.x; j < N; j += 256) {
        float l  = lin[(size_t)i * N + j];
        float sq = fmaxf(si + s[j] - 2.f * l, 0.f);
        float a  = expf(-0.5f * sq);
        acc += (j == i) ? 0.f : a;
    }
    __shared__ float red[256];
    red[threadIdx.x] = acc;
    __syncthreads();
    for (int o = 128; o > 0; o >>= 1) {
        if (threadIdx.x < o) red[threadIdx.x] += red[threadIdx.x + o];
        __syncthreads();
    }
    if (threadIdx.x == 0) rowsum[i] = red[0];
}

// ---------------------------------------------------------------------------
// In-place: lin -> e*lin + f*studentT + g*poly + h*graph
// ---------------------------------------------------------------------------
__global__ __launch_bounds__(256)
void combine_kernel(float* __restrict__ lin_io,
                    const float* __restrict__ s, const float* __restrict__ rowsum,
                    const float* __restrict__ ce, const float* __restrict__ cf,
                    const float* __restrict__ cg, const float* __restrict__ ch,
                    int N)
{
    int j = blockIdx.x * 256 + threadIdx.x;
    int i = blockIdx.y;
    size_t idx = (size_t)i * N + j;
    float l   = lin_io[idx];
    float sq  = fmaxf(s[i] + s[j] - 2.f * l, 0.f);
    float tk  = 1.f / (1.f + sq);
    float lp1 = l + 1.f;
    float pk  = lp1 * lp1;
    float a   = (i == j) ? 0.f : expf(-0.5f * sq);
    float di  = 1.f / sqrtf(rowsum[i] + 1e-12f);
    float dj  = 1.f / sqrtf(rowsum[j] + 1e-12f);
    float gk  = a * di * dj;
    lin_io[idx] = ce[idx] * l + cf[idx] * tk + cg[idx] * pk + ch[idx] * gk;
}

// ---------------------------------------------------------------------------
// k = a*kh1 + b*kh2 + c*kh3 + d*kz
// ---------------------------------------------------------------------------
__global__ __launch_bounds__(256)
void kcombine_kernel(const float4* __restrict__ kh1, const float4* __restrict__ kh2,
                     const float4* __restrict__ kh3, const float4* __restrict__ kz,
                     const float4* __restrict__ ca, const float4* __restrict__ cb,
                     const float4* __restrict__ cc, const float4* __restrict__ cd,
                     float4* __restrict__ out, int n4)
{
    int idx = blockIdx.x * 256 + threadIdx.x;
    if (idx >= n4) return;
    float4 A = ca[idx], B = cb[idx], C = cc[idx], D = cd[idx];
    float4 K1 = kh1[idx], K2 = kh2[idx], K3 = kh3[idx], KZ = kz[idx];
    float4 r;
    r.x = A.x * K1.x + B.x * K2.x + C.x * K3.x + D.x * KZ.x;
    r.y = A.y * K1.y + B.y * K2.y + C.y * K3.y + D.y * KZ.y;
    r.z = A.z * K1.z + B.z * K2.z + C.z * K3.z + D.z * KZ.z;
    r.w = A.w * K1.w + B.w * K2.w + C.w * K3.w + D.w * KZ.w;
    out[idx] = r;
}

// ---------------------------------------------------------------------------
// q[i][c][j] = k[i][j] - cluster[c][j]
// ---------------------------------------------------------------------------
__global__ __launch_bounds__(256)
void q_kernel(const float4* __restrict__ k, const float4* __restrict__ cl,
              float4* __restrict__ q, int N, int NC)
{
    int i  = blockIdx.y;
    int f4 = blockIdx.x * 256 + threadIdx.x;
    int n4 = N / 4;
    int c  = f4 / n4;
    int j4 = f4 - c * n4;
    float4 kv = k[(size_t)i * n4 + j4];
    float4 cv = cl[(size_t)c * n4 + j4];
    float4 r;
    r.x = kv.x - cv.x; r.y = kv.y - cv.y; r.z = kv.z - cv.z; r.w = kv.w - cv.w;
    q[((size_t)i * NC + c) * n4 + j4] = r;
}

// ---------------------------------------------------------------------------
// Launch
// ---------------------------------------------------------------------------
extern "C" void kernel_launch(void* const* d_in, const int* in_sizes, int n_in,
                              void* d_out, int out_size, void* d_ws, size_t ws_size,
                              hipStream_t stream)
{
    const int N = NN;
    const float* x     = (const float*)d_in[0];
    const float* Wenc1 = (const float*)d_in[1];
    const float* benc1 = (const float*)d_in[2];
    const float* Wenc2 = (const float*)d_in[3];
    const float* benc2 = (const float*)d_in[4];
    const float* Wenc3 = (const float*)d_in[5];
    const float* benc3 = (const float*)d_in[6];
    const float* Wz    = (const float*)d_in[7];
    const float* bz    = (const float*)d_in[8];
    const float* Wk1   = (const float*)d_in[9];
    const float* bk1   = (const float*)d_in[10];
    const float* Wk2   = (const float*)d_in[11];
    const float* bk2   = (const float*)d_in[12];
    const float* Wk3   = (const float*)d_in[13];
    const float* bk3   = (const float*)d_in[14];
    const float* Wk4   = (const float*)d_in[15];
    const float* bk4   = (const float*)d_in[16];
    const float* c_a  = (const float*)d_in[17];
    const float* c_b  = (const float*)d_in[18];
    const float* c_c  = (const float*)d_in[19];
    const float* c_d  = (const float*)d_in[20];
    const float* c_e  = (const float*)d_in[21];
    const float* c_f  = (const float*)d_in[22];
    const float* c_g  = (const float*)d_in[23];
    const float* c_h  = (const float*)d_in[24];
    const float* c_e1 = (const float*)d_in[25];
    const float* c_f1 = (const float*)d_in[26];
    const float* c_g1 = (const float*)d_in[27];
    const float* c_h1 = (const float*)d_in[28];
    const float* c_e2 = (const float*)d_in[29];
    const float* c_f2 = (const float*)d_in[30];
    const float* c_g2 = (const float*)d_in[31];
    const float* c_h2 = (const float*)d_in[32];
    const float* c_e3 = (const float*)d_in[33];
    const float* c_f3 = (const float*)d_in[34];
    const float* c_g3 = (const float*)d_in[35];
    const float* c_h3 = (const float*)d_in[36];
    const float* cluster = (const float*)d_in[37];

    float* out   = (float*)d_out;
    float* xbar  = out + 0;          // 3072*784
    float* k_out = out + 2408448;    // 3072*3072
    float* z_out = out + 11845632;   // 3072*10
    float* h1    = out + 11876352;   // 3072*500
    float* h2    = out + 13412352;   // 3072*500
    float* h3    = out + 14948352;   // 3072*2000
    float* q_out = out + 21092352;   // 3072*10*3072
    float* k22   = out + 115464192;  // 3072*500
    float* k33   = out + 117000192;  // 3072*500
    float* kh1   = out + 118536192;  // 3072*3072
    float* kh2   = out + 127973376;  // 3072*3072
    float* kh3   = out + 137410560;  // 3072*3072
    float* kz    = out + 146847744;  // 3072*3072

    float* ws = (float*)d_ws;
    float* k1 = ws;                  // 3072*2000
    float* s1 = ws + 6144000;
    float* s2 = s1 + N;
    float* s3 = s2 + N;
    float* sz = s3 + N;
    float* r1 = sz + N;
    float* r2 = r1 + N;
    float* r3 = r2 + N;
    float* rz = r3 + N;

    dim3 blk(256);
    auto gg = [](int m, int n) { return dim3((n + TBN - 1) / TBN, (m + TBM - 1) / TBM); };
    dim3 rowgrid(N);
    dim3 cgrid(N / 256, N);
    dim3 dgrid((N + 255) / 256);

    // ===== encoder layer 1 =====
    sgemm_kernel<false><<<gg(N, E1D), blk, 0, stream>>>(x, Wenc1, benc1, h1, N, E1D, NIN);
    sgemm_kernel<true ><<<gg(N, N),   blk, 0, stream>>>(h1, h1, nullptr, kh1, N, N, E1D);
    diag_kernel<<<dgrid, blk, 0, stream>>>(kh1, s1, N);
    rowsumA_kernel<<<rowgrid, blk, 0, stream>>>(kh1, s1, r1, N);
    combine_kernel<<<cgrid, blk, 0, stream>>>(kh1, s1, r1, c_e1, c_f1, c_g1, c_h1, N);

    // ===== encoder layer 2 =====
    sgemm_kernel<false><<<gg(N, E2D), blk, 0, stream>>>(h1, Wenc2, benc2, h2, N, E2D, E1D);
    sgemm_kernel<true ><<<gg(N, N),   blk, 0, stream>>>(h2, h2, nullptr, kh2, N, N, E2D);
    diag_kernel<<<dgrid, blk, 0, stream>>>(kh2, s2, N);
    rowsumA_kernel<<<rowgrid, blk, 0, stream>>>(kh2, s2, r2, N);
    combine_kernel<<<cgrid, blk, 0, stream>>>(kh2, s2, r2, c_e2, c_f2, c_g2, c_h2, N);

    // ===== encoder layer 3 =====
    sgemm_kernel<false><<<gg(N, E3D), blk, 0, stream>>>(h2, Wenc3, benc3, h3, N, E3D, E2D);
    sgemm_kernel<true ><<<gg(N, N),   blk, 0, stream>>>(h3, h3, nullptr, kh3, N, N, E3D);
    diag_kernel<<<dgrid, blk, 0, stream>>>(kh3, s3, N);
    rowsumA_kernel<<<rowgrid, blk, 0, stream>>>(kh3, s3, r3, N);
    combine_kernel<<<cgrid, blk, 0, stream>>>(kh3, s3, r3, c_e3, c_f3, c_g3, c_h3, N);

    // ===== latent z =====
    sgemm_kernel<false><<<gg(N, NZD), blk, 0, stream>>>(h3, Wz, bz, z_out, N, NZD, E3D);
    sgemm_kernel<true ><<<gg(N, N),   blk, 0, stream>>>(z_out, z_out, nullptr, kz, N, N, NZD);
    diag_kernel<<<dgrid, blk, 0, stream>>>(kz, sz, N);
    rowsumA_kernel<<<rowgrid, blk, 0, stream>>>(kz, sz, rz, N);
    combine_kernel<<<cgrid, blk, 0, stream>>>(kz, sz, rz, c_e, c_f, c_g, c_h, N);

    // ===== k = a*kh1 + b*kh2 + c*kh3 + d*kz =====
    {
        int n4 = N * N / 4;
        kcombine_kernel<<<dim3((n4 + 255) / 256), blk, 0, stream>>>(
            (const float4*)kh1, (const float4*)kh2, (const float4*)kh3, (const float4*)kz,
            (const float4*)c_a, (const float4*)c_b, (const float4*)c_c, (const float4*)c_d,
            (float4*)k_out, n4);
    }

    // ===== decoder chain =====
    sgemm_kernel<false><<<gg(N, 2000), blk, 0, stream>>>(k_out, Wk1, bk1, k1, N, 2000, N);
    sgemm_kernel<false><<<gg(N, 500),  blk, 0, stream>>>(k1, Wk2, bk2, k22, N, 500, 2000);
    sgemm_kernel<false><<<gg(N, 500),  blk, 0, stream>>>(k22, Wk3, bk3, k33, N, 500, 500);
    sgemm_kernel<false><<<gg(N, NIN),  blk, 0, stream>>>(k33, Wk4, bk4, xbar, N, NIN, 500);

    // ===== q = k[:,None,:] - cluster[None,:,:] =====
    {
        int per_i = NCD * N / 4;
        q_kernel<<<dim3(per_i / 256, N), blk, 0, stream>>>(
            (const float4*)k_out, (const float4*)cluster, (float4*)q_out, N, NCD);
    }
}